// Round 4
// baseline (1087.290 us; speedup 1.0000x reference)
//
#include <hip/hip_runtime.h>

// sign(tanh(conv1x1(x,W))) == sign(x @ W)
// x: [M=131072, K=512] f32, W: [K=512, N=32] f32, out: [M,N] f32 in {-1,0,1}
//
// Round-4 structure: reg-staged LDS tiling for x (padded XSTR=36 -> 0 bank
// conflicts, round-1-measured), double-buffered with T14 async-STAGE split
// (issue global->reg loads for chunk t+1 BEFORE computing chunk t; ds_write
// after compute; one barrier per chunk). W is read directly from global
// (L1/L2-hot 64 KB) to halve LDS-pipe traffic. 4x4 register tile per thread.
// |acc| < TAU recomputed in f64 wave-cooperatively -> exact sign.
//
// Journal: R2 source-swizzled global_load_lds = 6x/156x HBM amplification.
//          R3 LDS-free broadcast reuse = latency-bound (12% HBM, 17% VALU).

constexpr int K     = 512;
constexpr int N     = 32;
constexpr int BROWS = 128;          // rows/block -> grid 1024 = 4 blocks/CU
constexpr int KC    = 32;           // k-chunk
constexpr int XSTR  = KC + 4;       // padded LDS row stride (36 floats)
constexpr float TAU = 1e-3f;        // worst-case f32 dot error ~3e-4

__global__ __launch_bounds__(256, 4)
void conv_sign_kernel(const float* __restrict__ x,
                      const float* __restrict__ Wm,
                      float* __restrict__ out)
{
    __shared__ float xs[2][BROWS * XSTR];   // 2 x 18 KiB

    const int t = threadIdx.x;
    const int l = t & 63;
    const int w = t >> 6;
    const int block_row = blockIdx.x * BROWS;

    const int r0 = (t >> 3) << 2;   // 4 consecutive rows per thread
    const int c0 = (t & 7) << 2;    // 4 consecutive cols per thread

    // staging geometry: unit u = p*256 + t covers (row = u>>3, k4 = u&7)
    const int srow = t >> 3;        // + p*32
    const int sk   = (t & 7) << 2;  // float offset within row chunk

    float4 stg[4];
    auto issue = [&](int kc) {      // global -> reg, leave in flight
#pragma unroll
        for (int p = 0; p < 4; ++p) {
            const int row = p * 32 + srow;
            stg[p] = *reinterpret_cast<const float4*>(
                x + (size_t)(block_row + row) * K + kc + sk);
        }
    };
    auto commit = [&](int buf) {    // reg -> LDS (padded layout)
#pragma unroll
        for (int p = 0; p < 4; ++p) {
            const int row = p * 32 + srow;
            *reinterpret_cast<float4*>(&xs[buf][row * XSTR + sk]) = stg[p];
        }
    };

    float acc[4][4];
#pragma unroll
    for (int i = 0; i < 4; ++i)
#pragma unroll
        for (int j = 0; j < 4; ++j) acc[i][j] = 0.f;

    issue(0);
    commit(0);
    __syncthreads();

    const int NCHUNK = K / KC;      // 16
    for (int tc = 0; tc < NCHUNK; ++tc) {
        const int cur = tc & 1;
        if (tc + 1 < NCHUNK) issue((tc + 1) * KC);   // prefetch next chunk

        const float* xb = &xs[cur][r0 * XSTR];
        const float* wb = Wm + tc * KC * N + c0;     // W straight from global
#pragma unroll
        for (int k4 = 0; k4 < KC / 4; ++k4) {
            float4 xv[4], wv[4];
#pragma unroll
            for (int i = 0; i < 4; ++i)
                xv[i] = *reinterpret_cast<const float4*>(xb + i * XSTR + k4 * 4);
#pragma unroll
            for (int j = 0; j < 4; ++j)
                wv[j] = *reinterpret_cast<const float4*>(wb + (k4 * 4 + j) * N);
#pragma unroll
            for (int i = 0; i < 4; ++i) {
#pragma unroll
                for (int j = 0; j < 4; ++j) {
                    const float xk = (&xv[i].x)[j];
                    acc[i][0] += xk * wv[j].x;
                    acc[i][1] += xk * wv[j].y;
                    acc[i][2] += xk * wv[j].z;
                    acc[i][3] += xk * wv[j].w;
                }
            }
        }

        if (tc + 1 < NCHUNK) {
            commit(cur ^ 1);        // vmcnt wait folds here; loads had ~1k cy
            __syncthreads();        // one barrier per chunk
        }
    }

    // ---- exact f64 fixup for ambiguous accumulators (rare) ----
#pragma unroll
    for (int ai = 0; ai < 4; ++ai) {
#pragma unroll
        for (int bi = 0; bi < 4; ++bi) {
            unsigned long long bal = __ballot(fabsf(acc[ai][bi]) < TAU);
            while (bal) {
                const int s = __ffsll(bal) - 1;
                bal &= bal - 1;
                const int gr = block_row + 32 * w + ((s >> 3) << 2) + ai;
                const int gc = ((s & 7) << 2) + bi;
                const float* xr = x  + (size_t)gr * K + l * 8;
                const float* wr = Wm + (size_t)(l * 8) * N + gc;
                double part = 0.0;
#pragma unroll
                for (int q = 0; q < 8; ++q)
                    part += (double)xr[q] * (double)wr[q * N];
#pragma unroll
                for (int off = 32; off > 0; off >>= 1)
                    part += __shfl_xor(part, off);
                if (l == s)
                    acc[ai][bi] = (part > 0.0) ? 2.f : ((part < 0.0) ? -2.f : 0.f);
            }
        }
    }

    // ---- sign + store: 8 col-lane groups cover a 128B output row ----
#pragma unroll
    for (int i = 0; i < 4; ++i) {
        const int gr = block_row + r0 + i;
        float4 o;
        o.x = (acc[i][0] > 0.f) ? 1.f : ((acc[i][0] < 0.f) ? -1.f : 0.f);
        o.y = (acc[i][1] > 0.f) ? 1.f : ((acc[i][1] < 0.f) ? -1.f : 0.f);
        o.z = (acc[i][2] > 0.f) ? 1.f : ((acc[i][2] < 0.f) ? -1.f : 0.f);
        o.w = (acc[i][3] > 0.f) ? 1.f : ((acc[i][3] < 0.f) ? -1.f : 0.f);
        *reinterpret_cast<float4*>(out + (size_t)gr * N + c0) = o;
    }
}

extern "C" void kernel_launch(void* const* d_in, const int* in_sizes, int n_in,
                              void* d_out, int out_size, void* d_ws, size_t ws_size,
                              hipStream_t stream)
{
    const float* x  = (const float*)d_in[0];
    const float* Wm = (const float*)d_in[1];
    float* out      = (float*)d_out;
    const int M     = in_sizes[0] / K;            // 131072
    const int grid  = M / BROWS;                  // 1024
    hipLaunchKernelGGL(conv_sign_kernel, dim3(grid), dim3(256), 0, stream,
                       x, Wm, out);
}

// Round 5
// 110.285 us; speedup vs baseline: 9.8589x; 9.8589x over previous
//
#include <hip/hip_runtime.h>

// sign(tanh(conv1x1(x,W))) == sign(x @ W)
// x: [M=131072, K=512] f32, W: [K=512, N=32] f32, out: [M,N] f32 in {-1,0,1}
//
// R5: single-buffered LDS x-tile (padded XSTR=36, measured conflict-free in
// R4), simple stage->barrier->compute->barrier chunks. NO prefetch state held
// across compute (R2/R4 lesson: spill tripwire = WRITE_SIZE >> output bytes).
// Latency hiding comes from TLP: grid 1024, 18 KB LDS, no minwave bound ->
// ~6 blocks/CU at independent chunk phases. W is read from global (L1-hot,
// 8-group broadcast) to keep the LDS pipe under the HBM floor.
// |acc| < TAU recomputed in f64 wave-cooperatively -> exact sign.

constexpr int K     = 512;
constexpr int N     = 32;
constexpr int BROWS = 128;          // rows/block -> grid 1024
constexpr int KC    = 32;           // k-chunk
constexpr int XSTR  = KC + 4;       // padded LDS row stride (36 floats)
constexpr float TAU = 1e-3f;        // worst-case f32 dot error ~3e-4

__global__ __launch_bounds__(256)
void conv_sign_kernel(const float* __restrict__ x,
                      const float* __restrict__ Wm,
                      float* __restrict__ out)
{
    __shared__ float xs[BROWS * XSTR];   // 18 KiB

    const int t = threadIdx.x;
    const int l = t & 63;
    const int w = t >> 6;
    const int block_row = blockIdx.x * BROWS;

    const int r0 = (t >> 3) << 2;   // 4 consecutive rows per thread
    const int c0 = (t & 7) << 2;    // 4 consecutive cols per thread

    const int srow = t >> 3;        // staging row (+ p*32)
    const int sk   = (t & 7) << 2;  // staging float offset within row chunk

    float acc[4][4];
#pragma unroll
    for (int i = 0; i < 4; ++i)
#pragma unroll
        for (int j = 0; j < 4; ++j) acc[i][j] = 0.f;

    for (int tc = 0; tc < K / KC; ++tc) {
        const int kc = tc * KC;
        if (tc > 0) __syncthreads();          // prev compute done

        // ---- stage x chunk: 4 coalesced float4 loads -> LDS (transient regs) ----
        {
            float4 s0 = *reinterpret_cast<const float4*>(x + (size_t)(block_row +   0 + srow) * K + kc + sk);
            float4 s1 = *reinterpret_cast<const float4*>(x + (size_t)(block_row +  32 + srow) * K + kc + sk);
            float4 s2 = *reinterpret_cast<const float4*>(x + (size_t)(block_row +  64 + srow) * K + kc + sk);
            float4 s3 = *reinterpret_cast<const float4*>(x + (size_t)(block_row +  96 + srow) * K + kc + sk);
            *reinterpret_cast<float4*>(&xs[(  0 + srow) * XSTR + sk]) = s0;
            *reinterpret_cast<float4*>(&xs[( 32 + srow) * XSTR + sk]) = s1;
            *reinterpret_cast<float4*>(&xs[( 64 + srow) * XSTR + sk]) = s2;
            *reinterpret_cast<float4*>(&xs[( 96 + srow) * XSTR + sk]) = s3;
        }
        __syncthreads();                      // staged chunk visible

        const float* xb = &xs[r0 * XSTR];
        const float* wb = Wm + kc * N + c0;   // W straight from global (L1-hot)
#pragma unroll
        for (int k4 = 0; k4 < KC / 4; ++k4) {
            float4 xv[4], wv[4];
#pragma unroll
            for (int i = 0; i < 4; ++i)
                xv[i] = *reinterpret_cast<const float4*>(xb + i * XSTR + k4 * 4);
#pragma unroll
            for (int j = 0; j < 4; ++j)
                wv[j] = *reinterpret_cast<const float4*>(wb + (k4 * 4 + j) * N);
#pragma unroll
            for (int i = 0; i < 4; ++i) {
#pragma unroll
                for (int j = 0; j < 4; ++j) {
                    const float xk = (&xv[i].x)[j];
                    acc[i][0] += xk * wv[j].x;
                    acc[i][1] += xk * wv[j].y;
                    acc[i][2] += xk * wv[j].z;
                    acc[i][3] += xk * wv[j].w;
                }
            }
        }
    }

    // ---- exact f64 fixup for ambiguous accumulators (rare) ----
#pragma unroll
    for (int ai = 0; ai < 4; ++ai) {
#pragma unroll
        for (int bi = 0; bi < 4; ++bi) {
            unsigned long long bal = __ballot(fabsf(acc[ai][bi]) < TAU);
            while (bal) {
                const int s = __ffsll(bal) - 1;
                bal &= bal - 1;
                const int gr = block_row + 32 * w + ((s >> 3) << 2) + ai;
                const int gc = ((s & 7) << 2) + bi;
                const float* xr = x  + (size_t)gr * K + l * 8;
                const float* wr = Wm + (size_t)(l * 8) * N + gc;
                double part = 0.0;
#pragma unroll
                for (int q = 0; q < 8; ++q)
                    part += (double)xr[q] * (double)wr[q * N];
#pragma unroll
                for (int off = 32; off > 0; off >>= 1)
                    part += __shfl_xor(part, off);
                if (l == s)
                    acc[ai][bi] = (part > 0.0) ? 2.f : ((part < 0.0) ? -2.f : 0.f);
            }
        }
    }

    // ---- sign + store: 8 col-lane groups cover a 128B output row ----
#pragma unroll
    for (int i = 0; i < 4; ++i) {
        const int gr = block_row + r0 + i;
        float4 o;
        o.x = (acc[i][0] > 0.f) ? 1.f : ((acc[i][0] < 0.f) ? -1.f : 0.f);
        o.y = (acc[i][1] > 0.f) ? 1.f : ((acc[i][1] < 0.f) ? -1.f : 0.f);
        o.z = (acc[i][2] > 0.f) ? 1.f : ((acc[i][2] < 0.f) ? -1.f : 0.f);
        o.w = (acc[i][3] > 0.f) ? 1.f : ((acc[i][3] < 0.f) ? -1.f : 0.f);
        *reinterpret_cast<float4*>(out + (size_t)gr * N + c0) = o;
    }
}

extern "C" void kernel_launch(void* const* d_in, const int* in_sizes, int n_in,
                              void* d_out, int out_size, void* d_ws, size_t ws_size,
                              hipStream_t stream)
{
    const float* x  = (const float*)d_in[0];
    const float* Wm = (const float*)d_in[1];
    float* out      = (float*)d_out;
    const int M     = in_sizes[0] / K;            // 131072
    const int grid  = M / BROWS;                  // 1024
    hipLaunchKernelGGL(conv_sign_kernel, dim3(grid), dim3(256), 0, stream,
                       x, Wm, out);
}